// Round 4
// baseline (165.710 us; speedup 1.0000x reference)
//
#include <hip/hip_runtime.h>
#include <hip/hip_bf16.h>

static constexpr float kEps = 1e-6f;

typedef float f32x4 __attribute__((ext_vector_type(4)));

// Fused relu -> tp-sum -> RMSNorm, wave-per-row version.
// Each 64-lane wave owns one token row: 4096 floats = 16 f32x4 per lane held
// in registers. Sum-of-squares reduces with 6 __shfl_xor — no LDS, no
// __syncthreads, so every wave is an independent stream and load latency is
// hidden purely by TLP+ILP. NT stores keep the write stream out of L2.
template <int TP, int ITERS>  // ITERS = hidden / (64*4)
__global__ __launch_bounds__(256) void relu_ar_rmsnorm_wave(
    const float* __restrict__ x,      // [TP, tokens, hidden]
    const float* __restrict__ w,      // [hidden]
    float* __restrict__ out,          // [tokens, hidden]
    int tokens, int hidden)
{
    const int lane = threadIdx.x & 63;
    const int gwave = (blockIdx.x * (int)blockDim.x + threadIdx.x) >> 6;
    const int nwaves = (gridDim.x * (int)blockDim.x) >> 6;
    const long long rstride = (long long)tokens * hidden;

    for (int rowi = gwave; rowi < tokens; rowi += nwaves) {
        const long long row = (long long)rowi * hidden;

        f32x4 r[ITERS];
        float sumsq = 0.f;

#pragma unroll
        for (int i = 0; i < ITERS; ++i) {
            const int e = (i * 64 + lane) * 4;   // lane-contiguous: 1 KB per wave load
            f32x4 s = (f32x4)(0.f);
#pragma unroll
            for (int rk = 0; rk < TP; ++rk) {
                const f32x4 a = *reinterpret_cast<const f32x4*>(x + rk * rstride + row + e);
                s.x += fmaxf(a.x, 0.f);
                s.y += fmaxf(a.y, 0.f);
                s.z += fmaxf(a.z, 0.f);
                s.w += fmaxf(a.w, 0.f);
            }
            r[i] = s;
            sumsq += s.x * s.x + s.y * s.y + s.z * s.z + s.w * s.w;
        }

        // full-wave butterfly reduce (64 lanes)
#pragma unroll
        for (int off = 32; off >= 1; off >>= 1)
            sumsq += __shfl_xor(sumsq, off, 64);

        const float scale = rsqrtf(sumsq / (float)hidden + kEps);

#pragma unroll
        for (int i = 0; i < ITERS; ++i) {
            const int e = (i * 64 + lane) * 4;
            const f32x4 wv = *reinterpret_cast<const f32x4*>(w + e);
            f32x4 o;
            o.x = r[i].x * scale * wv.x;
            o.y = r[i].y * scale * wv.y;
            o.z = r[i].z * scale * wv.z;
            o.w = r[i].w * scale * wv.w;
            __builtin_nontemporal_store(o, reinterpret_cast<f32x4*>(out + row + e));
        }
    }
}

// Generic fallback (any tp / hidden): two-pass over the input row, scalar.
__global__ void relu_ar_rmsnorm_generic(
    const float* __restrict__ x,
    const float* __restrict__ w,
    float* __restrict__ out,
    int tp, int tokens, int hidden)
{
    const int tid = threadIdx.x;
    const long long row = (long long)blockIdx.x * hidden;
    const long long rstride = (long long)tokens * hidden;

    float sumsq = 0.f;
    for (int e = tid; e < hidden; e += blockDim.x) {
        float s = 0.f;
        for (int rk = 0; rk < tp; ++rk)
            s += fmaxf(x[rk * rstride + row + e], 0.f);
        sumsq += s * s;
    }
#pragma unroll
    for (int off = 32; off >= 1; off >>= 1)
        sumsq += __shfl_xor(sumsq, off, 64);

    __shared__ float wsum[16];
    const int nwaves = (blockDim.x + 63) >> 6;
    if ((tid & 63) == 0) wsum[tid >> 6] = sumsq;
    __syncthreads();
    float total = 0.f;
    for (int i = 0; i < nwaves; ++i) total += wsum[i];
    const float scale = rsqrtf(total / (float)hidden + kEps);

    for (int e = tid; e < hidden; e += blockDim.x) {
        float s = 0.f;
        for (int rk = 0; rk < tp; ++rk)
            s += fmaxf(x[rk * rstride + row + e], 0.f);
        out[row + e] = s * scale * w[e];
    }
}

extern "C" void kernel_launch(void* const* d_in, const int* in_sizes, int n_in,
                              void* d_out, int out_size, void* d_ws, size_t ws_size,
                              hipStream_t stream) {
    const float* x = (const float*)d_in[0];
    const float* w = (const float*)d_in[1];
    float* out = (float*)d_out;

    const int hidden = in_sizes[1];            // 4096
    const int tokens = out_size / hidden;      // 8192
    const int tp = in_sizes[0] / out_size;     // 4

    if (tp == 4 && hidden == 4096) {
        // one row per wave; 4 waves per 256-thread block
        const int nblocks = (tokens + 3) / 4;
        const int grid = nblocks < 2048 ? nblocks : 2048;
        relu_ar_rmsnorm_wave<4, 16><<<dim3(grid), dim3(256), 0, stream>>>(
            x, w, out, tokens, hidden);
    } else {
        relu_ar_rmsnorm_generic<<<dim3(tokens), dim3(256), 0, stream>>>(
            x, w, out, tp, tokens, hidden);
    }
}

// Round 5
// 113.028 us; speedup vs baseline: 1.4661x; 1.4661x over previous
//
#include <hip/hip_runtime.h>
#include <hip/hip_bf16.h>

static constexpr float kEps = 1e-6f;

typedef float f32x4 __attribute__((ext_vector_type(4)));

// Fused relu -> tp-sum -> RMSNorm, persistent-grid block-per-row (R3 structure).
// R4 lesson: wave-per-row (64 VGPR row residency) halved occupancy and lost
// 34% — block-per-row with r[4] keeps VGPR ~64 and 8 blocks/CU.
// This round: nontemporal LOADS on x (read-once, keep out of L2 allocate
// path) + single barrier per row via parity-indexed wsum.
template <int TP, int ITERS>
__global__ __launch_bounds__(256) void relu_ar_rmsnorm_persistent(
    const float* __restrict__ x,      // [TP, tokens, hidden]
    const float* __restrict__ w,      // [hidden]
    float* __restrict__ out,          // [tokens, hidden]
    int tokens, int hidden)
{
    const int tid = threadIdx.x;
    const long long rstride = (long long)tokens * hidden;

    __shared__ float wsum[2][4];
    int par = 0;

    for (int rowi = blockIdx.x; rowi < tokens; rowi += gridDim.x) {
        const long long row = (long long)rowi * hidden;

        f32x4 r[ITERS];
        float sumsq = 0.f;

#pragma unroll
        for (int i = 0; i < ITERS; ++i) {
            const int e = (i * 256 + tid) * 4;
            f32x4 s = (f32x4)(0.f);
#pragma unroll
            for (int rk = 0; rk < TP; ++rk) {
                const f32x4 a = __builtin_nontemporal_load(
                    reinterpret_cast<const f32x4*>(x + rk * rstride + row + e));
                s.x += fmaxf(a.x, 0.f);
                s.y += fmaxf(a.y, 0.f);
                s.z += fmaxf(a.z, 0.f);
                s.w += fmaxf(a.w, 0.f);
            }
            r[i] = s;
            sumsq += s.x * s.x + s.y * s.y + s.z * s.z + s.w * s.w;
        }

        // 64-lane butterfly reduce within each wave
#pragma unroll
        for (int off = 32; off >= 1; off >>= 1)
            sumsq += __shfl_xor(sumsq, off, 64);

        // cross-wave reduce (4 waves), single barrier via parity buffer:
        // a wave may run ahead into the next row; it writes wsum[par^1],
        // never the buffer still being read here.
        if ((tid & 63) == 0) wsum[par][tid >> 6] = sumsq;
        __syncthreads();
        const float total = wsum[par][0] + wsum[par][1] + wsum[par][2] + wsum[par][3];
        par ^= 1;

        const float scale = rsqrtf(total / (float)hidden + kEps);

#pragma unroll
        for (int i = 0; i < ITERS; ++i) {
            const int e = (i * 256 + tid) * 4;
            const f32x4 wv = *reinterpret_cast<const f32x4*>(w + e);
            f32x4 o;
            o.x = r[i].x * scale * wv.x;
            o.y = r[i].y * scale * wv.y;
            o.z = r[i].z * scale * wv.z;
            o.w = r[i].w * scale * wv.w;
            __builtin_nontemporal_store(o, reinterpret_cast<f32x4*>(out + row + e));
        }
    }
}

// Generic fallback (any tp / hidden): two-pass over the input row, scalar.
__global__ void relu_ar_rmsnorm_generic(
    const float* __restrict__ x,
    const float* __restrict__ w,
    float* __restrict__ out,
    int tp, int tokens, int hidden)
{
    const int tid = threadIdx.x;
    const long long row = (long long)blockIdx.x * hidden;
    const long long rstride = (long long)tokens * hidden;

    float sumsq = 0.f;
    for (int e = tid; e < hidden; e += blockDim.x) {
        float s = 0.f;
        for (int rk = 0; rk < tp; ++rk)
            s += fmaxf(x[rk * rstride + row + e], 0.f);
        sumsq += s * s;
    }
#pragma unroll
    for (int off = 32; off >= 1; off >>= 1)
        sumsq += __shfl_xor(sumsq, off, 64);

    __shared__ float wsum[16];
    const int nwaves = (blockDim.x + 63) >> 6;
    if ((tid & 63) == 0) wsum[tid >> 6] = sumsq;
    __syncthreads();
    float total = 0.f;
    for (int i = 0; i < nwaves; ++i) total += wsum[i];
    const float scale = rsqrtf(total / (float)hidden + kEps);

    for (int e = tid; e < hidden; e += blockDim.x) {
        float s = 0.f;
        for (int rk = 0; rk < tp; ++rk)
            s += fmaxf(x[rk * rstride + row + e], 0.f);
        out[row + e] = s * scale * w[e];
    }
}

extern "C" void kernel_launch(void* const* d_in, const int* in_sizes, int n_in,
                              void* d_out, int out_size, void* d_ws, size_t ws_size,
                              hipStream_t stream) {
    const float* x = (const float*)d_in[0];
    const float* w = (const float*)d_in[1];
    float* out = (float*)d_out;

    const int hidden = in_sizes[1];            // 4096
    const int tokens = out_size / hidden;      // 8192
    const int tp = in_sizes[0] / out_size;     // 4

    if (tp == 4 && hidden == 4096) {
        const int grid = tokens < 2048 ? tokens : 2048;
        relu_ar_rmsnorm_persistent<4, 4><<<dim3(grid), dim3(256), 0, stream>>>(
            x, w, out, tokens, hidden);
    } else {
        relu_ar_rmsnorm_generic<<<dim3(tokens), dim3(256), 0, stream>>>(
            x, w, out, tp, tokens, hidden);
    }
}